// Round 9
// baseline (167.936 us; speedup 1.0000x reference)
//
#include <hip/hip_runtime.h>

// B=1, H=W=128, C=1280; HW=16384 pixels, 19 relation channels, 1024 keys.
//
// Algebra: x_m = (v2@v1)·x   (M1 stored transposed m1t[c][o])
//          cab = softmax(x_m·imt^T)·im2, im2 = imt@inter  (1024x19)
//          out = relu((w2@w1)·cab) + x  (M2 stored transposed m2t[d][o])
//
// Fused kernel: 512 blocks x 32 px x 512 thr, 2 blocks/CU for phase overlap.
//
// ws layout (floats):
//   m1t : [1280][20] (pad)  off 0       (M1^T)
//   m2t : [19][1280]        off 25600
//   imt : [1024][20] (pad)  off 49920   (intra[i]^T)
//   im2 : [1024][20] (pad)  off 70400   (imt @ inter[i])

#define OFF_M2T 25600
#define OFF_IMT 49920
#define OFF_IM2 70400

typedef float vf4 __attribute__((ext_vector_type(4)));

// prep: weight folds + transposes + cls-row copy
__global__ __launch_bounds__(256) void prep_kernel(
    const float* __restrict__ v1, const float* __restrict__ v2,
    const float* __restrict__ w1, const float* __restrict__ w2,
    const float* __restrict__ intra, const float* __restrict__ inter,
    const int* __restrict__ ip, const float* __restrict__ x,
    float* __restrict__ out, float* __restrict__ ws)
{
  float* m1t = ws;
  float* m2t = ws + OFF_M2T;
  float* imt = ws + OFF_IMT;
  float* im2 = ws + OFF_IM2;
  const int blk = blockIdx.x, tid = threadIdx.x;
  if (blk < 380) {
    int g = blk * 256 + tid;
    int oidx = g >> 2, part = g & 3;
    int o = oidx / 1280, j = oidx - o * 1280;
    const float* v2r = v2 + o * 512 + part * 128;
    const float* v1c = v1 + part * 128 * 1280 + j;
    float acc = 0.f;
#pragma unroll 8
    for (int c = 0; c < 128; ++c) acc = fmaf(v2r[c], v1c[c * 1280], acc);
    acc += __shfl_xor(acc, 1);
    acc += __shfl_xor(acc, 2);
    if (part == 0) {
      m1t[j * 20 + o] = acc;
      if (o == 0) m1t[j * 20 + 19] = 0.f;
    }
  } else if (blk < 760) {
    int g = (blk - 380) * 256 + tid;
    int oidx = g >> 2, part = g & 3;
    int o = oidx / 19, d = oidx - o * 19;
    const float* w2r = w2 + o * 512 + part * 128;
    const float* w1c = w1 + part * 128 * 19 + d;
    float acc = 0.f;
#pragma unroll 8
    for (int c = 0; c < 128; ++c) acc = fmaf(w2r[c], w1c[c * 19], acc);
    acc += __shfl_xor(acc, 1);
    acc += __shfl_xor(acc, 2);
    if (part == 0) m2t[d * 1280 + o] = acc;
  } else if (blk < 836) {
    int t = (blk - 760) * 256 + tid;
    int c = t >> 10, k = t & 1023;
    int iv = *ip;
    imt[k * 20 + c] = intra[(size_t)iv * 19456 + c * 1024 + k];
    if (c == 0) imt[k * 20 + 19] = 0.f;
  } else if (blk < 912) {
    int t = (blk - 836) * 256 + tid;
    int d = t >> 10, k = t & 1023;
    int iv = *ip;
    const float* ib = intra + (size_t)iv * 19456 + k;
    const float* ir = inter + (size_t)iv * 361 + d;
    float acc = 0.f;
#pragma unroll
    for (int c = 0; c < 19; ++c) acc = fmaf(ib[c * 1024], ir[c * 19], acc);
    im2[k * 20 + d] = acc;
    if (d == 0) im2[k * 20 + 19] = 0.f;
  } else {
    const float4* xf = reinterpret_cast<const float4*>(x);
    float4* of = reinterpret_cast<float4*>(out);
    const int base = (blk - 912) * 1024 + tid;
#pragma unroll
    for (int q = 0; q < 4; ++q) of[base + q * 256] = xf[base + q * 256];
  }
}

// acc += XC * row, row given as 5 float4 quads (19 used)
#define FMA19Q(XC, q0, q1, q2, q3, q4)                                   \
  a00 = fmaf((XC), q0.x, a00); a01 = fmaf((XC), q0.y, a01);              \
  a02 = fmaf((XC), q0.z, a02); a03 = fmaf((XC), q0.w, a03);              \
  a04 = fmaf((XC), q1.x, a04); a05 = fmaf((XC), q1.y, a05);              \
  a06 = fmaf((XC), q1.z, a06); a07 = fmaf((XC), q1.w, a07);              \
  a08 = fmaf((XC), q2.x, a08); a09 = fmaf((XC), q2.y, a09);              \
  a10 = fmaf((XC), q2.z, a10); a11 = fmaf((XC), q2.w, a11);              \
  a12 = fmaf((XC), q3.x, a12); a13 = fmaf((XC), q3.y, a13);              \
  a14 = fmaf((XC), q3.z, a14); a15 = fmaf((XC), q3.w, a15);              \
  a16 = fmaf((XC), q4.x, a16); a17 = fmaf((XC), q4.y, a17);              \
  a18 = fmaf((XC), q4.z, a18);

#define LOADQ5(NM, PTR)                                                  \
  const float4 NM##0 = *reinterpret_cast<const float4*>(PTR);            \
  const float4 NM##1 = *reinterpret_cast<const float4*>((PTR) + 4);      \
  const float4 NM##2 = *reinterpret_cast<const float4*>((PTR) + 8);      \
  const float4 NM##3 = *reinterpret_cast<const float4*>((PTR) + 12);     \
  const float4 NM##4 = *reinterpret_cast<const float4*>((PTR) + 16);

// Fused: 512 thr (8 waves), 32 px/block, 512 blocks -> 2 blocks/CU overlap.
// Lane l: px = l&31, h = l>>5; wave kp. Weight reads are half-wave-uniform
// float4 global loads (2 addr/wave). Phase 3: 320 thr, mq[19] in registers.
__global__ __launch_bounds__(512, 4) void fused_kernel(
    const float* __restrict__ x, const float* __restrict__ ws,
    float* __restrict__ out)
{
  const float* m1t = ws;
  const float* m2t = ws + OFF_M2T;
  const float* imt = ws + OFF_IMT;
  const float* im2 = ws + OFF_IM2;

  __shared__ float smem[10752];   // stage 2x4096 | p1 red 16x608 | p2 red 16x672
  __shared__ float xmr[608];      // xm[px][19]
  __shared__ float cabs[640];     // cab[px][20] (16B-aligned rows)

  const int blk = blockIdx.x, tid = threadIdx.x;
  const int lane = tid & 63;
  const int px = lane & 31;
  const int h  = lane >> 5;                 // half-wave id (0/1)
  const int kp = tid >> 6;                  // wave 0..7
  const int kpu = __builtin_amdgcn_readfirstlane(kp);
  const int n0 = blk * 32;
  const float* xg = x + (size_t)(n0 + 128) * 1280;

  // ---------------- Phase 1: xm = M1 . x ----------------
  {
    // staging: 1024 float4/chunk; thread stages f=tid and f=tid+512
    const int f1 = tid + 512;
    const int spx0 = tid >> 5, sg0 = tid & 31;
    const int spx1 = f1 >> 5,  sg1 = f1 & 31;
    const size_t ga0 = (size_t)spx0 * 1280 + sg0 * 4;
    const size_t ga1 = (size_t)spx1 * 1280 + sg1 * 4;
    const int st0 = spx0 * 128 + (((sg0 + spx0) & 31) << 2);
    const int st1 = spx1 * 128 + (((sg1 + spx1) & 31) << 2);
    const int q0 = kpu * 4 + h * 2;
    const int rd0 = px * 128 + (((q0 + px) & 31) << 2);
    const int rd1 = px * 128 + (((q0 + 1 + px) & 31) << 2);

    float a00 = 0.f, a01 = 0.f, a02 = 0.f, a03 = 0.f, a04 = 0.f;
    float a05 = 0.f, a06 = 0.f, a07 = 0.f, a08 = 0.f, a09 = 0.f;
    float a10 = 0.f, a11 = 0.f, a12 = 0.f, a13 = 0.f, a14 = 0.f;
    float a15 = 0.f, a16 = 0.f, a17 = 0.f, a18 = 0.f;

    {
      const float4 r0 = *reinterpret_cast<const float4*>(xg + ga0);
      const float4 r1 = *reinterpret_cast<const float4*>(xg + ga1);
      *reinterpret_cast<float4*>(smem + st0) = r0;
      *reinterpret_cast<float4*>(smem + st1) = r1;
    }
    __syncthreads();

    for (int cc = 0; cc < 10; ++cc) {
      float4 nv0, nv1;
      if (cc < 9) {                  // issue next-chunk loads before compute
        nv0 = *reinterpret_cast<const float4*>(xg + ga0 + (cc + 1) * 128);
        nv1 = *reinterpret_cast<const float4*>(xg + ga1 + (cc + 1) * 128);
      }
      const float* buf = smem + (cc & 1) * 4096;
      const float4 xv0 = *reinterpret_cast<const float4*>(buf + rd0);
      const float4 xv1 = *reinterpret_cast<const float4*>(buf + rd1);
      // lane's 8 channels: c = cc*128 + kpu*16 + h*8 + j (half-wave-uniform rows)
      const float* mrow = m1t + (size_t)(cc * 128 + kpu * 16 + h * 8) * 20;
#pragma unroll
      for (int j = 0; j < 8; ++j) {
        const float* wr = mrow + j * 20;
        LOADQ5(w, wr);
        const float xc = (j < 4) ? reinterpret_cast<const float*>(&xv0)[j]
                                 : reinterpret_cast<const float*>(&xv1)[j - 4];
        FMA19Q(xc, w0, w1, w2, w3, w4);
      }
      if (cc < 9) {
        float* nbuf = smem + ((cc + 1) & 1) * 4096;
        *reinterpret_cast<float4*>(nbuf + st0) = nv0;
        *reinterpret_cast<float4*>(nbuf + st1) = nv1;
      }
      __syncthreads();
    }

    {
      float* rb = smem + (kp * 2 + h) * 608 + px * 19;  // stride 19 coprime 32
      rb[0] = a00;  rb[1] = a01;  rb[2] = a02;  rb[3] = a03;  rb[4] = a04;
      rb[5] = a05;  rb[6] = a06;  rb[7] = a07;  rb[8] = a08;  rb[9] = a09;
      rb[10] = a10; rb[11] = a11; rb[12] = a12; rb[13] = a13; rb[14] = a14;
      rb[15] = a15; rb[16] = a16; rb[17] = a17; rb[18] = a18;
    }
    __syncthreads();
    for (int idx = tid; idx < 608; idx += 512) {
      float v = 0.f;
#pragma unroll
      for (int q = 0; q < 16; ++q) v += smem[q * 608 + idx];
      xmr[idx] = v;                     // idx == px*19 + o
    }
    __syncthreads();
  }

  // ---------------- Phase 2: softmax over 1024 keys ----------------
  {
    const float* xr = xmr + px * 19;
    const float x00 = xr[0],  x01 = xr[1],  x02 = xr[2],  x03 = xr[3];
    const float x04 = xr[4],  x05 = xr[5],  x06 = xr[6],  x07 = xr[7];
    const float x08 = xr[8],  x09 = xr[9],  x10 = xr[10], x11 = xr[11];
    const float x12 = xr[12], x13 = xr[13], x14 = xr[14], x15 = xr[15];
    const float x16 = xr[16], x17 = xr[17], x18 = xr[18];

    float a00 = 0.f, a01 = 0.f, a02 = 0.f, a03 = 0.f, a04 = 0.f;
    float a05 = 0.f, a06 = 0.f, a07 = 0.f, a08 = 0.f, a09 = 0.f;
    float a10 = 0.f, a11 = 0.f, a12 = 0.f, a13 = 0.f, a14 = 0.f;
    float a15 = 0.f, a16 = 0.f, a17 = 0.f, a18 = 0.f;
    float Z = 0.f;
    const int kb = kpu * 128 + h * 64;    // half-wave-uniform key base
    for (int it = 0; it < 64; ++it) {
      const float* wp = imt + (size_t)(kb + it) * 20;
      const float* up = im2 + (size_t)(kb + it) * 20;
      LOADQ5(w, wp);
      LOADQ5(u, up);
      float s0 = x00 * w0.x;
      s0 = fmaf(x04, w1.x, s0); s0 = fmaf(x08, w2.x, s0);
      s0 = fmaf(x12, w3.x, s0); s0 = fmaf(x16, w4.x, s0);
      float s1 = x01 * w0.y;
      s1 = fmaf(x05, w1.y, s1); s1 = fmaf(x09, w2.y, s1);
      s1 = fmaf(x13, w3.y, s1); s1 = fmaf(x17, w4.y, s1);
      float s2 = x02 * w0.z;
      s2 = fmaf(x06, w1.z, s2); s2 = fmaf(x10, w2.z, s2);
      s2 = fmaf(x14, w3.z, s2); s2 = fmaf(x18, w4.z, s2);
      float s3 = x03 * w0.w;
      s3 = fmaf(x07, w1.w, s3); s3 = fmaf(x11, w3.w * 0.f + w3.w, s3); // placeholder avoided
      s3 = fmaf(x11, 0.f, s3);
      const float sc = 0.f;
      (void)sc;
      // (rewritten below without tricks)
      float t3 = x03 * w0.w;
      t3 = fmaf(x07, w1.w, t3); t3 = fmaf(x11, w2.w, t3);
      t3 = fmaf(x15, w3.w, t3);
      const float sfull = (s0 + s1) + (s2 + t3);
      const float pv = __expf(sfull);
      Z += pv;
      FMA19Q(pv, u0, u1, u2, u3, u4);
    }
    {
      float* rb = smem + (kp * 2 + h) * 672 + px * 21;  // stride 21 coprime 32
      rb[0] = a00;  rb[1] = a01;  rb[2] = a02;  rb[3] = a03;  rb[4] = a04;
      rb[5] = a05;  rb[6] = a06;  rb[7] = a07;  rb[8] = a08;  rb[9] = a09;
      rb[10] = a10; rb[11] = a11; rb[12] = a12; rb[13] = a13; rb[14] = a14;
      rb[15] = a15; rb[16] = a16; rb[17] = a17; rb[18] = a18; rb[19] = Z;
    }
    __syncthreads();
    for (int idx = tid; idx < 608; idx += 512) {
      const int rr = idx / 19, d = idx - rr * 19;
      float v = 0.f, Zs = 0.f;
#pragma unroll
      for (int q = 0; q < 16; ++q) {
        v  += smem[q * 672 + rr * 21 + d];
        Zs += smem[q * 672 + rr * 21 + 19];
      }
      cabs[rr * 20 + d] = v / Zs;
    }
    __syncthreads();
  }

  // ---------------- Phase 3: out = relu(m2t . cab) + x ----------------
  if (tid < 320) {
    const int c4 = tid * 4;
    float4 mq[19];
#pragma unroll
    for (int d = 0; d < 19; ++d)
      mq[d] = *reinterpret_cast<const float4*>(m2t + d * 1280 + c4);
#pragma unroll 2
    for (int pxx = 0; pxx < 32; ++pxx) {
      const float* cb = cabs + pxx * 20;     // uniform -> LDS broadcast
      const float4 cb0 = *reinterpret_cast<const float4*>(cb);
      const float4 cb1 = *reinterpret_cast<const float4*>(cb + 4);
      const float4 cb2 = *reinterpret_cast<const float4*>(cb + 8);
      const float4 cb3 = *reinterpret_cast<const float4*>(cb + 12);
      const float4 cb4 = *reinterpret_cast<const float4*>(cb + 16);
      const float4 xv = *reinterpret_cast<const float4*>(
          xg + (size_t)pxx * 1280 + c4);
      const float cf[19] = {cb0.x, cb0.y, cb0.z, cb0.w, cb1.x, cb1.y, cb1.z,
                            cb1.w, cb2.x, cb2.y, cb2.z, cb2.w, cb3.x, cb3.y,
                            cb3.z, cb3.w, cb4.x, cb4.y, cb4.z};
      float4 a = make_float4(0.f, 0.f, 0.f, 0.f);
#pragma unroll
      for (int d = 0; d < 19; ++d) {
        const float f = cf[d];
        a.x = fmaf(mq[d].x, f, a.x);
        a.y = fmaf(mq[d].y, f, a.y);
        a.z = fmaf(mq[d].z, f, a.z);
        a.w = fmaf(mq[d].w, f, a.w);
      }
      vf4 o4;
      o4.x = fmaxf(a.x, 0.f) + xv.x;
      o4.y = fmaxf(a.y, 0.f) + xv.y;
      o4.z = fmaxf(a.z, 0.f) + xv.z;
      o4.w = fmaxf(a.w, 0.f) + xv.w;
      __builtin_nontemporal_store(
          o4, reinterpret_cast<vf4*>(out + (size_t)(n0 + pxx + 128) * 1280 + c4));
    }
  }
}

extern "C" void kernel_launch(void* const* d_in, const int* in_sizes, int n_in,
                              void* d_out, int out_size, void* d_ws, size_t ws_size,
                              hipStream_t stream)
{
  const float* x     = (const float*)d_in[0];
  const float* v1    = (const float*)d_in[1];
  const float* v2    = (const float*)d_in[2];
  const float* w1    = (const float*)d_in[3];
  const float* w2    = (const float*)d_in[4];
  const float* intra = (const float*)d_in[5];
  const float* inter = (const float*)d_in[6];
  const int*   ip    = (const int*)d_in[7];
  float* out = (float*)d_out;
  float* ws  = (float*)d_ws;

  prep_kernel<<<952, 256, 0, stream>>>(v1, v2, w1, w2, intra, inter, ip, x, out, ws);
  fused_kernel<<<512, 512, 0, stream>>>(x, ws, out);
}

// Round 10
// 97.354 us; speedup vs baseline: 1.7250x; 1.7250x over previous
//
#include <hip/hip_runtime.h>

// B=1, H=W=128, C=1280; HW=16384 pixels, 19 relation channels, 1024 keys.
//
// Algebra: x_m = (v2@v1)·x   (M1 stored transposed m1t[c][o])
//          cab = softmax(x_m·imt^T)·im2, im2 = imt@inter  (1024x19)
//          out = relu((w2@w1)·cab) + x  (M2 stored transposed m2t[d][o])
//
// Fused per-64-px-block kernel (row-local chain); xm/cab live in LDS.
// All weight-row reads are WAVE-UNIFORM -> s_loads (R9 lesson: half-wave
// splits turn these into per-lane VMEM loads, 2x regression).
//
// ws layout (floats):
//   m1t : [1280][20] (pad)  off 0       (M1^T: m1t[c][o])
//   m2t : [19][1280]        off 25600
//   imt : [1024][20] (pad)  off 49920   (intra[i]^T)
//   im2 : [1024][20] (pad)  off 70400   (imt @ inter[i])

#define OFF_M2T 25600
#define OFF_IMT 49920
#define OFF_IM2 70400

typedef float vf4 __attribute__((ext_vector_type(4)));

// prep: weight folds + transposes + cls-row copy
__global__ __launch_bounds__(256) void prep_kernel(
    const float* __restrict__ v1, const float* __restrict__ v2,
    const float* __restrict__ w1, const float* __restrict__ w2,
    const float* __restrict__ intra, const float* __restrict__ inter,
    const int* __restrict__ ip, const float* __restrict__ x,
    float* __restrict__ out, float* __restrict__ ws)
{
  float* m1t = ws;
  float* m2t = ws + OFF_M2T;
  float* imt = ws + OFF_IMT;
  float* im2 = ws + OFF_IM2;
  const int blk = blockIdx.x, tid = threadIdx.x;
  if (blk < 380) {
    int g = blk * 256 + tid;
    int oidx = g >> 2, part = g & 3;
    int o = oidx / 1280, j = oidx - o * 1280;
    const float* v2r = v2 + o * 512 + part * 128;
    const float* v1c = v1 + part * 128 * 1280 + j;
    float acc = 0.f;
#pragma unroll 8
    for (int c = 0; c < 128; ++c) acc = fmaf(v2r[c], v1c[c * 1280], acc);
    acc += __shfl_xor(acc, 1);
    acc += __shfl_xor(acc, 2);
    if (part == 0) {
      m1t[j * 20 + o] = acc;
      if (o == 0) m1t[j * 20 + 19] = 0.f;
    }
  } else if (blk < 760) {
    int g = (blk - 380) * 256 + tid;
    int oidx = g >> 2, part = g & 3;
    int o = oidx / 19, d = oidx - o * 19;
    const float* w2r = w2 + o * 512 + part * 128;
    const float* w1c = w1 + part * 128 * 19 + d;
    float acc = 0.f;
#pragma unroll 8
    for (int c = 0; c < 128; ++c) acc = fmaf(w2r[c], w1c[c * 19], acc);
    acc += __shfl_xor(acc, 1);
    acc += __shfl_xor(acc, 2);
    if (part == 0) m2t[d * 1280 + o] = acc;
  } else if (blk < 836) {
    int t = (blk - 760) * 256 + tid;
    int c = t >> 10, k = t & 1023;
    int iv = *ip;
    imt[k * 20 + c] = intra[(size_t)iv * 19456 + c * 1024 + k];
    if (c == 0) imt[k * 20 + 19] = 0.f;
  } else if (blk < 912) {
    int t = (blk - 836) * 256 + tid;
    int d = t >> 10, k = t & 1023;
    int iv = *ip;
    const float* ib = intra + (size_t)iv * 19456 + k;
    const float* ir = inter + (size_t)iv * 361 + d;
    float acc = 0.f;
#pragma unroll
    for (int c = 0; c < 19; ++c) acc = fmaf(ib[c * 1024], ir[c * 19], acc);
    im2[k * 20 + d] = acc;
    if (d == 0) im2[k * 20 + 19] = 0.f;
  } else {
    const float4* xf = reinterpret_cast<const float4*>(x);
    float4* of = reinterpret_cast<float4*>(out);
    const int base = (blk - 912) * 1024 + tid;
#pragma unroll
    for (int q = 0; q < 4; ++q) of[base + q * 256] = xf[base + q * 256];
  }
}

#define XM_FMA19(XC, W)                                                  \
  a00 = fmaf((XC), (W)[0],  a00); a01 = fmaf((XC), (W)[1],  a01);        \
  a02 = fmaf((XC), (W)[2],  a02); a03 = fmaf((XC), (W)[3],  a03);        \
  a04 = fmaf((XC), (W)[4],  a04); a05 = fmaf((XC), (W)[5],  a05);        \
  a06 = fmaf((XC), (W)[6],  a06); a07 = fmaf((XC), (W)[7],  a07);        \
  a08 = fmaf((XC), (W)[8],  a08); a09 = fmaf((XC), (W)[9],  a09);        \
  a10 = fmaf((XC), (W)[10], a10); a11 = fmaf((XC), (W)[11], a11);        \
  a12 = fmaf((XC), (W)[12], a12); a13 = fmaf((XC), (W)[13], a13);        \
  a14 = fmaf((XC), (W)[14], a14); a15 = fmaf((XC), (W)[15], a15);        \
  a16 = fmaf((XC), (W)[16], a16); a17 = fmaf((XC), (W)[17], a17);        \
  a18 = fmaf((XC), (W)[18], a18);

// acc += PA*UA[d] + PB*UB[d]  (two independent softmax key streams)
#define SOFT_ACC2(PA, UA, PB, UB)                                          \
  a00 = fmaf((PA), (UA)[0],  fmaf((PB), (UB)[0],  a00));                   \
  a01 = fmaf((PA), (UA)[1],  fmaf((PB), (UB)[1],  a01));                   \
  a02 = fmaf((PA), (UA)[2],  fmaf((PB), (UB)[2],  a02));                   \
  a03 = fmaf((PA), (UA)[3],  fmaf((PB), (UB)[3],  a03));                   \
  a04 = fmaf((PA), (UA)[4],  fmaf((PB), (UB)[4],  a04));                   \
  a05 = fmaf((PA), (UA)[5],  fmaf((PB), (UB)[5],  a05));                   \
  a06 = fmaf((PA), (UA)[6],  fmaf((PB), (UB)[6],  a06));                   \
  a07 = fmaf((PA), (UA)[7],  fmaf((PB), (UB)[7],  a07));                   \
  a08 = fmaf((PA), (UA)[8],  fmaf((PB), (UB)[8],  a08));                   \
  a09 = fmaf((PA), (UA)[9],  fmaf((PB), (UB)[9],  a09));                   \
  a10 = fmaf((PA), (UA)[10], fmaf((PB), (UB)[10], a10));                   \
  a11 = fmaf((PA), (UA)[11], fmaf((PB), (UB)[11], a11));                   \
  a12 = fmaf((PA), (UA)[12], fmaf((PB), (UB)[12], a12));                   \
  a13 = fmaf((PA), (UA)[13], fmaf((PB), (UB)[13], a13));                   \
  a14 = fmaf((PA), (UA)[14], fmaf((PB), (UB)[14], a14));                   \
  a15 = fmaf((PA), (UA)[15], fmaf((PB), (UB)[15], a15));                   \
  a16 = fmaf((PA), (UA)[16], fmaf((PB), (UB)[16], a16));                   \
  a17 = fmaf((PA), (UA)[17], fmaf((PB), (UB)[17], a17));                   \
  a18 = fmaf((PA), (UA)[18], fmaf((PB), (UB)[18], a18));

// 19-element dot of (x00..x18) with wave-uniform row W -> result in SF
#define DOT19(SF, W)                                                       \
  {                                                                        \
    float d0 = x00 * (W)[0];                                               \
    d0 = fmaf(x04, (W)[4],  d0); d0 = fmaf(x08, (W)[8],  d0);              \
    d0 = fmaf(x12, (W)[12], d0); d0 = fmaf(x16, (W)[16], d0);              \
    float d1 = x01 * (W)[1];                                               \
    d1 = fmaf(x05, (W)[5],  d1); d1 = fmaf(x09, (W)[9],  d1);              \
    d1 = fmaf(x13, (W)[13], d1); d1 = fmaf(x17, (W)[17], d1);              \
    float d2 = x02 * (W)[2];                                               \
    d2 = fmaf(x06, (W)[6],  d2); d2 = fmaf(x10, (W)[10], d2);              \
    d2 = fmaf(x14, (W)[14], d2); d2 = fmaf(x18, (W)[18], d2);              \
    float d3 = x03 * (W)[3];                                               \
    d3 = fmaf(x07, (W)[7],  d3); d3 = fmaf(x11, (W)[11], d3);              \
    d3 = fmaf(x15, (W)[15], d3);                                           \
    SF = (d0 + d1) + (d2 + d3);                                            \
  }

// Fused per-64-pixel-block kernel: 1024 threads, 1 block/CU (~92 KB LDS).
// launch_bounds(1024,4): we can only ever have 4 waves/EU (LDS-bound), so
// let the allocator use up to 128 VGPR (prevents the 64-VGPR self-cap that
// forced m2t re-loads in phase 3).
__global__ __launch_bounds__(1024, 4) void fused_kernel(
    const float* __restrict__ x, const float* __restrict__ ws,
    float* __restrict__ out)
{
  const float* m1t = ws;
  const float* m2t = ws + OFF_M2T;
  const float* imt = ws + OFF_IMT;
  const float* im2 = ws + OFF_IM2;

  __shared__ float smem[20480];   // p1: 2x8192 stage + 16x1216 red; p2: red[16][64][20]
  __shared__ float xmr[1216];     // xm[px][19]
  __shared__ float cabs[1280];    // cab[px][20] (16B-aligned rows)

  const int blk = blockIdx.x, tid = threadIdx.x;
  const int p  = tid & 63;
  const int kp = tid >> 6;
  const int kpu = __builtin_amdgcn_readfirstlane(kp);
  const int n0 = blk * 64;
  const float* xg = x + (size_t)(n0 + 128) * 1280;

  // ---------------- Phase 1: xm = M1 . x ----------------
  {
    const int px0 = tid >> 5, g0 = tid & 31;
    const int px1 = px0 + 32;
    const size_t ga0 = (size_t)px0 * 1280 + g0 * 4;
    const size_t ga1 = (size_t)px1 * 1280 + g0 * 4;
    const int st0 = px0 * 128 + (((g0 + px0) & 31) << 2);
    const int st1 = px1 * 128 + (((g0 + px1) & 31) << 2);
    const int rd0 = p * 128 + ((((kpu * 2 + 0) + p) & 31) << 2);
    const int rd1 = p * 128 + ((((kpu * 2 + 1) + p) & 31) << 2);

    float a00 = 0.f, a01 = 0.f, a02 = 0.f, a03 = 0.f, a04 = 0.f;
    float a05 = 0.f, a06 = 0.f, a07 = 0.f, a08 = 0.f, a09 = 0.f;
    float a10 = 0.f, a11 = 0.f, a12 = 0.f, a13 = 0.f, a14 = 0.f;
    float a15 = 0.f, a16 = 0.f, a17 = 0.f, a18 = 0.f;

    {
      const float4 rA0 = *reinterpret_cast<const float4*>(xg + ga0);
      const float4 rA1 = *reinterpret_cast<const float4*>(xg + ga1);
      *reinterpret_cast<float4*>(smem + st0) = rA0;
      *reinterpret_cast<float4*>(smem + st1) = rA1;
    }
    __syncthreads();

    for (int cc = 0; cc < 10; ++cc) {
      float4 nv0, nv1;
      if (cc < 9) {                    // issue next-chunk loads before compute
        nv0 = *reinterpret_cast<const float4*>(xg + ga0 + (cc + 1) * 128);
        nv1 = *reinterpret_cast<const float4*>(xg + ga1 + (cc + 1) * 128);
      }
      const float* buf = smem + (cc & 1) * 8192;
      const float4 xv0 = *reinterpret_cast<const float4*>(buf + rd0);
      const float4 xv1 = *reinterpret_cast<const float4*>(buf + rd1);
      const float* wrow = m1t + (cc * 128 + kpu * 8) * 20;   // uniform -> s_load
      XM_FMA19(xv0.x, wrow);
      XM_FMA19(xv0.y, wrow + 20);
      XM_FMA19(xv0.z, wrow + 40);
      XM_FMA19(xv0.w, wrow + 60);
      XM_FMA19(xv1.x, wrow + 80);
      XM_FMA19(xv1.y, wrow + 100);
      XM_FMA19(xv1.z, wrow + 120);
      XM_FMA19(xv1.w, wrow + 140);
      if (cc < 9) {
        float* nbuf = smem + ((cc + 1) & 1) * 8192;
        *reinterpret_cast<float4*>(nbuf + st0) = nv0;
        *reinterpret_cast<float4*>(nbuf + st1) = nv1;
      }
      __syncthreads();
    }

    {
      float* rb = smem + kp * 1216 + p * 19;   // stride 19 coprime 32
      rb[0] = a00;  rb[1] = a01;  rb[2] = a02;  rb[3] = a03;  rb[4] = a04;
      rb[5] = a05;  rb[6] = a06;  rb[7] = a07;  rb[8] = a08;  rb[9] = a09;
      rb[10] = a10; rb[11] = a11; rb[12] = a12; rb[13] = a13; rb[14] = a14;
      rb[15] = a15; rb[16] = a16; rb[17] = a17; rb[18] = a18;
    }
    __syncthreads();
    for (int idx = tid; idx < 1216; idx += 1024) {
      const int o = idx >> 6, pp = idx & 63;
      float s = 0.f;
#pragma unroll
      for (int q = 0; q < 16; ++q) s += smem[q * 1216 + pp * 19 + o];
      xmr[pp * 19 + o] = s;
    }
    __syncthreads();
  }

  // ---------------- Phase 2: softmax over 1024 keys (paired streams) ----------------
  {
    const float* xr = xmr + p * 19;
    const float x00 = xr[0],  x01 = xr[1],  x02 = xr[2],  x03 = xr[3];
    const float x04 = xr[4],  x05 = xr[5],  x06 = xr[6],  x07 = xr[7];
    const float x08 = xr[8],  x09 = xr[9],  x10 = xr[10], x11 = xr[11];
    const float x12 = xr[12], x13 = xr[13], x14 = xr[14], x15 = xr[15];
    const float x16 = xr[16], x17 = xr[17], x18 = xr[18];

    float a00 = 0.f, a01 = 0.f, a02 = 0.f, a03 = 0.f, a04 = 0.f;
    float a05 = 0.f, a06 = 0.f, a07 = 0.f, a08 = 0.f, a09 = 0.f;
    float a10 = 0.f, a11 = 0.f, a12 = 0.f, a13 = 0.f, a14 = 0.f;
    float a15 = 0.f, a16 = 0.f, a17 = 0.f, a18 = 0.f;
    float Z = 0.f;
    const int kb = kpu * 64;
    for (int it = 0; it < 32; ++it) {
      const float* wA = imt + (size_t)(kb + it) * 20;        // uniform -> s_load
      const float* wB = imt + (size_t)(kb + 32 + it) * 20;
      const float* uA = im2 + (size_t)(kb + it) * 20;
      const float* uB = im2 + (size_t)(kb + 32 + it) * 20;
      float sA, sB;
      DOT19(sA, wA);
      DOT19(sB, wB);
      const float pA = __expf(sA);
      const float pB = __expf(sB);
      Z += pA + pB;
      SOFT_ACC2(pA, uA, pB, uB);
    }
    {
      float* rb = smem + kp * 1280 + p * 20;   // red[16][64][20]
      rb[0] = a00;  rb[1] = a01;  rb[2] = a02;  rb[3] = a03;  rb[4] = a04;
      rb[5] = a05;  rb[6] = a06;  rb[7] = a07;  rb[8] = a08;  rb[9] = a09;
      rb[10] = a10; rb[11] = a11; rb[12] = a12; rb[13] = a13; rb[14] = a14;
      rb[15] = a15; rb[16] = a16; rb[17] = a17; rb[18] = a18; rb[19] = Z;
    }
    __syncthreads();
    for (int idx = tid; idx < 1216; idx += 1024) {
      const int rr = idx / 19, d = idx - rr * 19;
      float s = 0.f, Zs = 0.f;
#pragma unroll
      for (int q = 0; q < 16; ++q) {
        s  += smem[q * 1280 + rr * 20 + d];
        Zs += smem[q * 1280 + rr * 20 + 19];
      }
      cabs[rr * 20 + d] = s / Zs;
    }
    __syncthreads();
  }

  // ---------------- Phase 3: out = relu(m2t . cab) + x (paired px) ----------------
  if (tid < 960) {
    const int pg   = tid / 320;        // pixel group 0..2
    const int quad = tid - pg * 320;   // c-quad 0..319 (lane-consecutive)
    const int c4 = quad * 4;
    float4 mq[19];
#pragma unroll
    for (int d = 0; d < 19; ++d)
      mq[d] = *reinterpret_cast<const float4*>(m2t + d * 1280 + c4);
    for (int pxA = pg; pxA < 64; pxA += 6) {
      const int pxB = pxA + 3;
      const bool hasB = (pxB < 64);
      // issue both x loads up front
      const float4 xvA = *reinterpret_cast<const float4*>(
          xg + (size_t)pxA * 1280 + c4);
      float4 xvB = xvA;
      if (hasB)
        xvB = *reinterpret_cast<const float4*>(xg + (size_t)pxB * 1280 + c4);

      const float* cbA = cabs + pxA * 20;          // wave-uniform LDS rows
      const float4 cA0 = *reinterpret_cast<const float4*>(cbA);
      const float4 cA1 = *reinterpret_cast<const float4*>(cbA + 4);
      const float4 cA2 = *reinterpret_cast<const float4*>(cbA + 8);
      const float4 cA3 = *reinterpret_cast<const float4*>(cbA + 12);
      const float4 cA4 = *reinterpret_cast<const float4*>(cbA + 16);
      const float cfA[19] = {cA0.x, cA0.y, cA0.z, cA0.w, cA1.x, cA1.y, cA1.z,
                             cA1.w, cA2.x, cA2.y, cA2.z, cA2.w, cA3.x, cA3.y,
                             cA3.z, cA3.w, cA4.x, cA4.y, cA4.z};
      float4 aa = make_float4(0.f, 0.f, 0.f, 0.f);
#pragma unroll
      for (int d = 0; d < 19; ++d) {
        const float f = cfA[d];
        aa.x = fmaf(mq[d].x, f, aa.x);
        aa.y = fmaf(mq[d].y, f, aa.y);
        aa.z = fmaf(mq[d].z, f, aa.z);
        aa.w = fmaf(mq[d].w, f, aa.w);
      }
      vf4 oA;
      oA.x = fmaxf(aa.x, 0.f) + xvA.x;
      oA.y = fmaxf(aa.y, 0.f) + xvA.y;
      oA.z = fmaxf(aa.z, 0.f) + xvA.z;
      oA.w = fmaxf(aa.w, 0.f) + xvA.w;
      __builtin_nontemporal_store(
          oA, reinterpret_cast<vf4*>(out + (size_t)(n0 + pxA + 128) * 1280 + c4));

      if (hasB) {
        const float* cbB = cabs + pxB * 20;
        const float4 cB0 = *reinterpret_cast<const float4*>(cbB);
        const float4 cB1 = *reinterpret_cast<const float4*>(cbB + 4);
        const float4 cB2 = *reinterpret_cast<const float4*>(cbB + 8);
        const float4 cB3 = *reinterpret_cast<const float4*>(cbB + 12);
        const float4 cB4 = *reinterpret_cast<const float4*>(cbB + 16);
        const float cfB[19] = {cB0.x, cB0.y, cB0.z, cB0.w, cB1.x, cB1.y, cB1.z,
                               cB1.w, cB2.x, cB2.y, cB2.z, cB2.w, cB3.x, cB3.y,
                               cB3.z, cB3.w, cB4.x, cB4.y, cB4.z};
        float4 ab = make_float4(0.f, 0.f, 0.f, 0.f);
#pragma unroll
        for (int d = 0; d < 19; ++d) {
          const float f = cfB[d];
          ab.x = fmaf(mq[d].x, f, ab.x);
          ab.y = fmaf(mq[d].y, f, ab.y);
          ab.z = fmaf(mq[d].z, f, ab.z);
          ab.w = fmaf(mq[d].w, f, ab.w);
        }
        vf4 oB;
        oB.x = fmaxf(ab.x, 0.f) + xvB.x;
        oB.y = fmaxf(ab.y, 0.f) + xvB.y;
        oB.z = fmaxf(ab.z, 0.f) + xvB.z;
        oB.w = fmaxf(ab.w, 0.f) + xvB.w;
        __builtin_nontemporal_store(
            oB, reinterpret_cast<vf4*>(out + (size_t)(n0 + pxB + 128) * 1280 + c4));
      }
    }
  }
}

extern "C" void kernel_launch(void* const* d_in, const int* in_sizes, int n_in,
                              void* d_out, int out_size, void* d_ws, size_t ws_size,
                              hipStream_t stream)
{
  const float* x     = (const float*)d_in[0];
  const float* v1    = (const float*)d_in[1];
  const float* v2    = (const float*)d_in[2];
  const float* w1    = (const float*)d_in[3];
  const float* w2    = (const float*)d_in[4];
  const float* intra = (const float*)d_in[5];
  const float* inter = (const float*)d_in[6];
  const int*   ip    = (const int*)d_in[7];
  float* out = (float*)d_out;
  float* ws  = (float*)d_ws;

  prep_kernel<<<952, 256, 0, stream>>>(v1, v2, w1, w2, intra, inter, ip, x, out, ws);
  fused_kernel<<<256, 1024, 0, stream>>>(x, ws, out);
}

// Round 11
// 97.341 us; speedup vs baseline: 1.7252x; 1.0001x over previous
//
#include <hip/hip_runtime.h>

// B=1, H=W=128, C=1280; HW=16384 px, 19 relation channels, 1024 keys.
//
// Algebra: x_m = (v2@v1)·x ; cab = softmax(x_m·imt^T)·im2 ; out = relu((w2@w1)·cab)+x
// Fused per-64-px-block kernel. All dot products via v_dot2_f32_f16
// (weights stored f16-packed by prep; fp32 accumulate everywhere).
//
// ws as _Float16 halves:
//   m1h : [19][1280]          off 0      len 24320   (M1[o][c], f16)
//   m2h : [1280][24] (pad)    off 24320  len 30720   (M2[c][d], f16, 48B rows)
//   wh  : [1024][24] (pad)    off 55040  len 24576   (intra[i]^T keys, f16)
//   u2h : [512][40]           off 79616  len 20480   (im2 key-pair interleaved:
//                                                     u2h[k/2][d*2+(k&1)])
#define M1H 0
#define M2H 24320
#define WH  55040
#define U2H 79616

typedef float vf4 __attribute__((ext_vector_type(4)));
typedef _Float16 half2v __attribute__((ext_vector_type(2)));

static __device__ __forceinline__ float fd2(half2v a, half2v b, float c) {
  return __builtin_amdgcn_fdot2(a, b, c, false);
}
static __device__ __forceinline__ half2v h2(float f) {
  return __builtin_bit_cast(half2v, f);
}
static __device__ __forceinline__ unsigned pkh(float a, float b) {
  return __builtin_bit_cast(unsigned, __builtin_amdgcn_cvt_pkrtz(a, b));
}
static __device__ __forceinline__ half2v uh(unsigned u) {
  return __builtin_bit_cast(half2v, u);
}

// prep: weight folds -> f16 layouts + cls-row copy
__global__ __launch_bounds__(256) void prep_kernel(
    const float* __restrict__ v1, const float* __restrict__ v2,
    const float* __restrict__ w1, const float* __restrict__ w2,
    const float* __restrict__ intra, const float* __restrict__ inter,
    const int* __restrict__ ip, const float* __restrict__ x,
    float* __restrict__ out, _Float16* __restrict__ wsH)
{
  _Float16* m1h = wsH + M1H;
  _Float16* m2h = wsH + M2H;
  _Float16* wh  = wsH + WH;
  _Float16* u2h = wsH + U2H;
  const int blk = blockIdx.x, tid = threadIdx.x;
  if (blk < 380) {
    // M1[o][j] = sum_c v2[o][c]*v1[c][j], 4-way c-split + shfl reduce
    int g = blk * 256 + tid;
    int oidx = g >> 2, part = g & 3;
    int o = oidx / 1280, j = oidx - o * 1280;
    const float* v2r = v2 + o * 512 + part * 128;
    const float* v1c = v1 + part * 128 * 1280 + j;
    float acc = 0.f;
#pragma unroll 8
    for (int c = 0; c < 128; ++c) acc = fmaf(v2r[c], v1c[c * 1280], acc);
    acc += __shfl_xor(acc, 1);
    acc += __shfl_xor(acc, 2);
    if (part == 0) m1h[o * 1280 + j] = (_Float16)acc;
  } else if (blk < 760) {
    // M2[o][d] = sum_c w2[o][c]*w1[c][d]  (o = output channel 0..1279)
    int g = (blk - 380) * 256 + tid;
    int oidx = g >> 2, part = g & 3;
    int o = oidx / 19, d = oidx - o * 19;
    const float* w2r = w2 + o * 512 + part * 128;
    const float* w1c = w1 + part * 128 * 19 + d;
    float acc = 0.f;
#pragma unroll 8
    for (int c = 0; c < 128; ++c) acc = fmaf(w2r[c], w1c[c * 19], acc);
    acc += __shfl_xor(acc, 1);
    acc += __shfl_xor(acc, 2);
    if (part == 0) {
      m2h[o * 24 + d] = (_Float16)acc;
      if (d == 0)
#pragma unroll
        for (int t = 19; t < 24; ++t) m2h[o * 24 + t] = (_Float16)0.f;
    }
  } else if (blk < 836) {
    // wh[k][c] = intra[i][c][k]
    int t = (blk - 760) * 256 + tid;
    int c = t >> 10, k = t & 1023;
    int iv = *ip;
    wh[k * 24 + c] = (_Float16)intra[(size_t)iv * 19456 + c * 1024 + k];
    if (c == 0)
#pragma unroll
      for (int q = 19; q < 24; ++q) wh[k * 24 + q] = (_Float16)0.f;
  } else if (blk < 912) {
    // im2[k][d] = sum_c intra[i][c][k]*inter[i][c][d], key-pair interleaved
    int t = (blk - 836) * 256 + tid;
    int d = t >> 10, k = t & 1023;
    int iv = *ip;
    const float* ib = intra + (size_t)iv * 19456 + k;
    const float* ir = inter + (size_t)iv * 361 + d;
    float acc = 0.f;
#pragma unroll
    for (int c = 0; c < 19; ++c) acc = fmaf(ib[c * 1024], ir[c * 19], acc);
    u2h[(k >> 1) * 40 + d * 2 + (k & 1)] = (_Float16)acc;
    if (d == 0 && (k & 1) == 0) {
      u2h[(k >> 1) * 40 + 38] = (_Float16)0.f;
      u2h[(k >> 1) * 40 + 39] = (_Float16)0.f;
    }
  } else {
    // cls row copy
    const float4* xf = reinterpret_cast<const float4*>(x);
    float4* of = reinterpret_cast<float4*>(out);
    const int base = (blk - 912) * 1024 + tid;
#pragma unroll
    for (int q = 0; q < 4; ++q) of[base + q * 256] = xf[base + q * 256];
  }
}

// one output channel o of phase-1: 4 fdot2 against xq0..xq3
#define P1O(AC, O)                                                         \
  {                                                                        \
    const vf4 w = *reinterpret_cast<const vf4*>(m1row + (O)*1280);         \
    AC = fd2(xq0, h2(w[0]), AC);                                           \
    AC = fd2(xq1, h2(w[1]), AC);                                           \
    AC = fd2(xq2, h2(w[2]), AC);                                           \
    AC = fd2(xq3, h2(w[3]), AC);                                           \
  }

// 19-ch dot (xp0..xp9 half2) against 3 vf4 of f16 weights -> S
#define P2DOT(S, W0, W1, W2)                                               \
  {                                                                        \
    float e0 = fd2(xp0, h2(W0[0]), 0.f);                                   \
    e0 = fd2(xp2, h2(W0[2]), e0);                                          \
    e0 = fd2(xp4, h2(W1[0]), e0);                                          \
    e0 = fd2(xp6, h2(W1[2]), e0);                                          \
    e0 = fd2(xp8, h2(W2[0]), e0);                                          \
    float e1 = fd2(xp1, h2(W0[1]), 0.f);                                   \
    e1 = fd2(xp3, h2(W0[3]), e1);                                          \
    e1 = fd2(xp5, h2(W1[1]), e1);                                          \
    e1 = fd2(xp7, h2(W1[3]), e1);                                          \
    e1 = fd2(xp9, h2(W2[1]), e1);                                          \
    S = e0 + e1;                                                           \
  }

// PV accumulate of a key pair: 19 fdot2 with pp = (pA,pB)
#define P2PV(PP, U0, U1, U2, U3, U4)                                       \
  o00 = fd2(PP, h2(U0[0]), o00); o01 = fd2(PP, h2(U0[1]), o01);            \
  o02 = fd2(PP, h2(U0[2]), o02); o03 = fd2(PP, h2(U0[3]), o03);            \
  o04 = fd2(PP, h2(U1[0]), o04); o05 = fd2(PP, h2(U1[1]), o05);            \
  o06 = fd2(PP, h2(U1[2]), o06); o07 = fd2(PP, h2(U1[3]), o07);            \
  o08 = fd2(PP, h2(U2[0]), o08); o09 = fd2(PP, h2(U2[1]), o09);            \
  o10 = fd2(PP, h2(U2[2]), o10); o11 = fd2(PP, h2(U2[3]), o11);            \
  o12 = fd2(PP, h2(U3[0]), o12); o13 = fd2(PP, h2(U3[1]), o13);            \
  o14 = fd2(PP, h2(U3[2]), o14); o15 = fd2(PP, h2(U3[3]), o15);            \
  o16 = fd2(PP, h2(U4[0]), o16); o17 = fd2(PP, h2(U4[1]), o17);            \
  o18 = fd2(PP, h2(U4[2]), o18);

__global__ __launch_bounds__(1024, 4) void fused_kernel(
    const float* __restrict__ x, const _Float16* __restrict__ wsH,
    float* __restrict__ out)
{
  const _Float16* m1h = wsH + M1H;
  const _Float16* m2h = wsH + M2H;
  const _Float16* wh  = wsH + WH;
  const _Float16* u2h = wsH + U2H;

  __shared__ float smem[20480];       // stage (as halves) / p1 red / p2 red
  __shared__ float xmr[1216];         // xm[px][19] fp32
  __shared__ _Float16 cabs[1536];     // cab[px][24] f16 (48B rows)

  const int blk = blockIdx.x, tid = threadIdx.x;
  const int p  = tid & 63;
  const int kp = tid >> 6;
  const int kpu = __builtin_amdgcn_readfirstlane(kp);
  const int n0 = blk * 64;
  const float* xg = x + (size_t)(n0 + 128) * 1280;
  _Float16* xs = reinterpret_cast<_Float16*>(smem);

  // ---------------- Phase 1: xm = M1 . x (f16 dot2, fp32 acc) ----------------
  {
    const int px0 = tid >> 5, g0 = tid & 31;
    const int px1 = px0 + 32;
    const size_t ga0 = (size_t)px0 * 1280 + g0 * 4;
    const size_t ga1 = (size_t)px1 * 1280 + g0 * 4;
    const int st0 = px0 * 128 + (((g0 + px0) & 31) << 2);  // half offsets
    const int st1 = px1 * 128 + (((g0 + px1) & 31) << 2);
    const int rd0 = p * 128 + ((((kpu * 2 + 0) + p) & 31) << 2);
    const int rd1 = p * 128 + ((((kpu * 2 + 1) + p) & 31) << 2);

    float a00 = 0.f, a01 = 0.f, a02 = 0.f, a03 = 0.f, a04 = 0.f;
    float a05 = 0.f, a06 = 0.f, a07 = 0.f, a08 = 0.f, a09 = 0.f;
    float a10 = 0.f, a11 = 0.f, a12 = 0.f, a13 = 0.f, a14 = 0.f;
    float a15 = 0.f, a16 = 0.f, a17 = 0.f, a18 = 0.f;

    {
      const float4 r0 = *reinterpret_cast<const float4*>(xg + ga0);
      const float4 r1 = *reinterpret_cast<const float4*>(xg + ga1);
      uint2 u0; u0.x = pkh(r0.x, r0.y); u0.y = pkh(r0.z, r0.w);
      uint2 u1; u1.x = pkh(r1.x, r1.y); u1.y = pkh(r1.z, r1.w);
      *reinterpret_cast<uint2*>(xs + st0) = u0;
      *reinterpret_cast<uint2*>(xs + st1) = u1;
    }
    __syncthreads();

    for (int cc = 0; cc < 10; ++cc) {
      float4 nv0, nv1;
      if (cc < 9) {                    // next-chunk loads before compute
        nv0 = *reinterpret_cast<const float4*>(xg + ga0 + (cc + 1) * 128);
        nv1 = *reinterpret_cast<const float4*>(xg + ga1 + (cc + 1) * 128);
      }
      const _Float16* buf = xs + (cc & 1) * 8192;
      const uint2 r0 = *reinterpret_cast<const uint2*>(buf + rd0);
      const uint2 r1 = *reinterpret_cast<const uint2*>(buf + rd1);
      const half2v xq0 = uh(r0.x), xq1 = uh(r0.y);
      const half2v xq2 = uh(r1.x), xq3 = uh(r1.y);
      const _Float16* m1row = m1h + cc * 128 + kpu * 8;   // wave-uniform
      P1O(a00, 0);  P1O(a01, 1);  P1O(a02, 2);  P1O(a03, 3);  P1O(a04, 4);
      P1O(a05, 5);  P1O(a06, 6);  P1O(a07, 7);  P1O(a08, 8);  P1O(a09, 9);
      P1O(a10, 10); P1O(a11, 11); P1O(a12, 12); P1O(a13, 13); P1O(a14, 14);
      P1O(a15, 15); P1O(a16, 16); P1O(a17, 17); P1O(a18, 18);
      if (cc < 9) {
        _Float16* nbuf = xs + ((cc + 1) & 1) * 8192;
        uint2 u0; u0.x = pkh(nv0.x, nv0.y); u0.y = pkh(nv0.z, nv0.w);
        uint2 u1; u1.x = pkh(nv1.x, nv1.y); u1.y = pkh(nv1.z, nv1.w);
        *reinterpret_cast<uint2*>(nbuf + st0) = u0;
        *reinterpret_cast<uint2*>(nbuf + st1) = u1;
      }
      __syncthreads();
    }

    {
      float* rb = smem + kp * 1216 + p * 19;   // stride 19 coprime 32
      rb[0] = a00;  rb[1] = a01;  rb[2] = a02;  rb[3] = a03;  rb[4] = a04;
      rb[5] = a05;  rb[6] = a06;  rb[7] = a07;  rb[8] = a08;  rb[9] = a09;
      rb[10] = a10; rb[11] = a11; rb[12] = a12; rb[13] = a13; rb[14] = a14;
      rb[15] = a15; rb[16] = a16; rb[17] = a17; rb[18] = a18;
    }
    __syncthreads();
    for (int idx = tid; idx < 1216; idx += 1024) {
      const int o = idx >> 6, pp = idx & 63;
      float s = 0.f;
#pragma unroll
      for (int q = 0; q < 16; ++q) s += smem[q * 1216 + pp * 19 + o];
      xmr[pp * 19 + o] = s;
    }
    __syncthreads();
  }

  // ---------------- Phase 2: softmax over 1024 keys (key-pair dot2) ----------------
  {
    const float* xr = xmr + p * 19;
    const half2v xp0 = uh(pkh(xr[0],  xr[1]));
    const half2v xp1 = uh(pkh(xr[2],  xr[3]));
    const half2v xp2 = uh(pkh(xr[4],  xr[5]));
    const half2v xp3 = uh(pkh(xr[6],  xr[7]));
    const half2v xp4 = uh(pkh(xr[8],  xr[9]));
    const half2v xp5 = uh(pkh(xr[10], xr[11]));
    const half2v xp6 = uh(pkh(xr[12], xr[13]));
    const half2v xp7 = uh(pkh(xr[14], xr[15]));
    const half2v xp8 = uh(pkh(xr[16], xr[17]));
    const half2v xp9 = uh(pkh(xr[18], 0.f));

    float o00 = 0.f, o01 = 0.f, o02 = 0.f, o03 = 0.f, o04 = 0.f;
    float o05 = 0.f, o06 = 0.f, o07 = 0.f, o08 = 0.f, o09 = 0.f;
    float o10 = 0.f, o11 = 0.f, o12 = 0.f, o13 = 0.f, o14 = 0.f;
    float o15 = 0.f, o16 = 0.f, o17 = 0.f, o18 = 0.f;
    float Z = 0.f;
    const int kb = kpu * 64;
    for (int it = 0; it < 32; ++it) {
      const int kA = kb + 2 * it;
      const vf4* wfA = reinterpret_cast<const vf4*>(wh + kA * 24);
      const vf4* wfB = reinterpret_cast<const vf4*>(wh + (kA + 1) * 24);
      const vf4* uf  = reinterpret_cast<const vf4*>(u2h + (size_t)(kA >> 1) * 40);
      const vf4 wA0 = wfA[0], wA1 = wfA[1], wA2 = wfA[2];
      const vf4 wB0 = wfB[0], wB1 = wfB[1], wB2 = wfB[2];
      const vf4 U0 = uf[0], U1 = uf[1], U2 = uf[2], U3 = uf[3], U4 = uf[4];
      float sA, sB;
      P2DOT(sA, wA0, wA1, wA2);
      P2DOT(sB, wB0, wB1, wB2);
      const float pA = __expf(sA);
      const float pB = __expf(sB);
      Z += pA + pB;
      const half2v pp = uh(pkh(pA, pB));
      P2PV(pp, U0, U1, U2, U3, U4);
    }
    {
      float* rb = smem + kp * 1280 + p * 20;   // red[16][64][20]
      rb[0] = o00;  rb[1] = o01;  rb[2] = o02;  rb[3] = o03;  rb[4] = o04;
      rb[5] = o05;  rb[6] = o06;  rb[7] = o07;  rb[8] = o08;  rb[9] = o09;
      rb[10] = o10; rb[11] = o11; rb[12] = o12; rb[13] = o13; rb[14] = o14;
      rb[15] = o15; rb[16] = o16; rb[17] = o17; rb[18] = o18; rb[19] = Z;
    }
    __syncthreads();
    for (int idx = tid; idx < 1216; idx += 1024) {
      const int rr = idx / 19, d = idx - rr * 19;
      float s = 0.f, Zs = 0.f;
#pragma unroll
      for (int q = 0; q < 16; ++q) {
        s  += smem[q * 1280 + rr * 20 + d];
        Zs += smem[q * 1280 + rr * 20 + 19];
      }
      cabs[rr * 24 + d] = (_Float16)(s / Zs);
      if (d == 0) {
#pragma unroll
        for (int t = 19; t < 24; ++t) cabs[rr * 24 + t] = (_Float16)0.f;
      }
    }
    __syncthreads();
  }

  // ---------------- Phase 3: out = relu(m2h . cab) + x ----------------
  if (tid < 960) {
    const int pg   = tid / 320;
    const int quad = tid - pg * 320;
    const int c4 = quad * 4;
    // thread's 4 channel rows of M2 (f16): 12 vf4, contiguous 192 B
    vf4 mq[12];
    {
      const vf4* mf = reinterpret_cast<const vf4*>(m2h + (size_t)c4 * 24);
#pragma unroll
      for (int i = 0; i < 12; ++i) mq[i] = mf[i];
    }
    float4 xnext = *reinterpret_cast<const float4*>(xg + (size_t)pg * 1280 + c4);
    for (int px = pg; px < 64; px += 3) {
      const float4 xv = xnext;
      const int pxn = px + 3;
      if (pxn < 64)
        xnext = *reinterpret_cast<const float4*>(xg + (size_t)pxn * 1280 + c4);
      const vf4* cb = reinterpret_cast<const vf4*>(cabs + px * 24);  // uniform
      const vf4 C0 = cb[0], C1 = cb[1], C2 = cb[2];
      const half2v c0 = h2(C0[0]), c1 = h2(C0[1]), c2 = h2(C0[2]), c3 = h2(C0[3]);
      const half2v c4h = h2(C1[0]), c5 = h2(C1[1]), c6 = h2(C1[2]), c7 = h2(C1[3]);
      const half2v c8 = h2(C2[0]), c9 = h2(C2[1]);
      float acc[4];
#pragma unroll
      for (int j = 0; j < 4; ++j) {
        float t0 = fd2(c0, h2(mq[3 * j][0]), 0.f);
        t0 = fd2(c2, h2(mq[3 * j][2]), t0);
        t0 = fd2(c4h, h2(mq[3 * j + 1][0]), t0);
        t0 = fd2(c6, h2(mq[3 * j + 1][2]), t0);
        t0 = fd2(c8, h2(mq[3 * j + 2][0]), t0);
        float t1 = fd2(c1, h2(mq[3 * j][1]), 0.f);
        t1 = fd2(c3, h2(mq[3 * j][3]), t1);
        t1 = fd2(c5, h2(mq[3 * j + 1][1]), t1);
        t1 = fd2(c7, h2(mq[3 * j + 1][3]), t1);
        t1 = fd2(c9, h2(mq[3 * j + 2][1]), t1);
        acc[j] = t0 + t1;
      }
      vf4 o4;
      o4[0] = fmaxf(acc[0], 0.f) + xv.x;
      o4[1] = fmaxf(acc[1], 0.f) + xv.y;
      o4[2] = fmaxf(acc[2], 0.f) + xv.z;
      o4[3] = fmaxf(acc[3], 0.f) + xv.w;
      __builtin_nontemporal_store(
          o4, reinterpret_cast<vf4*>(out + (size_t)(n0 + px + 128) * 1280 + c4));
    }
  }
}

extern "C" void kernel_launch(void* const* d_in, const int* in_sizes, int n_in,
                              void* d_out, int out_size, void* d_ws, size_t ws_size,
                              hipStream_t stream)
{
  const float* x     = (const float*)d_in[0];
  const float* v1    = (const float*)d_in[1];
  const float* v2    = (const float*)d_in[2];
  const float* w1    = (const float*)d_in[3];
  const float* w2    = (const float*)d_in[4];
  const float* intra = (const float*)d_in[5];
  const float* inter = (const float*)d_in[6];
  const int*   ip    = (const int*)d_in[7];
  float* out = (float*)d_out;
  _Float16* wsH = (_Float16*)d_ws;

  prep_kernel<<<952, 256, 0, stream>>>(v1, v2, w1, w2, intra, inter, ip, x, out, wsH);
  fused_kernel<<<256, 1024, 0, stream>>>(x, wsH, out);
}